// Round 1
// 942.931 us; speedup vs baseline: 1.0772x; 1.0772x over previous
//
#include <hip/hip_runtime.h>

#define NN 50000
#define NE 800000

typedef __attribute__((ext_vector_type(8))) short short8;
typedef __attribute__((ext_vector_type(4))) float floatx4;

__device__ __forceinline__ unsigned short f2b(float f){
  unsigned u = __float_as_uint(f);
  u += 0x7fffu + ((u >> 16) & 1u);
  return (unsigned short)(u >> 16);
}
__device__ __forceinline__ float blo(unsigned u){ return __uint_as_float(u << 16); }
__device__ __forceinline__ float bhi(unsigned u){ return __uint_as_float(u & 0xffff0000u); }

// ---------------- fused prep: nf->bf16, hist, weight swizzles ----------------
// (ef is now consumed as f32 directly by k_agg1 -- no efb conversion pass)
// packed B layout (stride 32): dst[((k>>5)*N + n)*32 + (k&31)]
#define NB_NF   3125           // NN*64/4 float4 / 256
#define NB_HIST 3125           // NE/256
#define NB_W1A  96             // 192*128/256
#define NB_W1E  128            // 128*256/256
#define NB_W2A  192            // 384*128/256
#define NB_W2E  128

__global__ __launch_bounds__(256) void k_prep(const float* __restrict__ nf,
                                              const float* __restrict__ W1a,
                                              const float* __restrict__ W1e,
                                              const float* __restrict__ W2a,
                                              const float* __restrict__ W2e,
                                              const int* __restrict__ v,
                                              unsigned short* __restrict__ nfb,
                                              unsigned short* __restrict__ w1as,
                                              unsigned short* __restrict__ w1es,
                                              unsigned short* __restrict__ w2as,
                                              unsigned short* __restrict__ w2es,
                                              int* __restrict__ cnt){
  int b = blockIdx.x, t = threadIdx.x;
  if(b < NB_NF){
    int i = b * 256 + t;
    float4 vv = ((const float4*)nf)[i];
    unsigned a = (unsigned)f2b(vv.x) | ((unsigned)f2b(vv.y) << 16);
    unsigned c = (unsigned)f2b(vv.z) | ((unsigned)f2b(vv.w) << 16);
    ((uint2*)nfb)[i] = make_uint2(a, c);
  } else if(b < NB_NF + NB_HIST){
    int e = (b - NB_NF) * 256 + t;
    if(e < NE) atomicAdd(&cnt[v[e]], 1);
  } else if(b < NB_NF + NB_HIST + NB_W1A){
    int i = (b - NB_NF - NB_HIST) * 256 + t;        // 192x128
    int k = i >> 7, n = i & 127;
    w1as[((k >> 5) * 128 + n) * 32 + (k & 31)] = f2b(W1a[i]);
  } else if(b < NB_NF + NB_HIST + NB_W1A + NB_W1E){
    int i = (b - NB_NF - NB_HIST - NB_W1A) * 256 + t; // 128x256 view of 256x128
    int k = i >> 8, n = i & 255;
    float val = W1e[(size_t)(k + ((n >> 7) << 7)) * 128 + (n & 127)];
    w1es[((k >> 5) * 256 + n) * 32 + (k & 31)] = f2b(val);
  } else if(b < NB_NF + NB_HIST + NB_W1A + NB_W1E + NB_W2A){
    int i = (b - NB_NF - NB_HIST - NB_W1A - NB_W1E) * 256 + t; // 384x128
    int k = i >> 7, n = i & 127;
    w2as[((k >> 5) * 128 + n) * 32 + (k & 31)] = f2b(W2a[i]);
  } else {
    int i = (b - NB_NF - NB_HIST - NB_W1A - NB_W1E - NB_W2A) * 256 + t;
    int k = i >> 8, n = i & 255;
    float val = W2e[(size_t)(k + ((n >> 7) << 7)) * 128 + (n & 127)];
    w2es[((k >> 5) * 256 + n) * 32 + (k & 31)] = f2b(val);
  }
}

// ---------------- CSR scan + fill ----------------
__global__ __launch_bounds__(512) void k_scanA(const int* __restrict__ cnt,
                                               int* __restrict__ rowptr,
                                               int* __restrict__ part){
  __shared__ int lds[512];
  int t = threadIdx.x;
  int i = blockIdx.x * 512 + t;
  int x = (i < NN) ? cnt[i] : 0;
  lds[t] = x;
  __syncthreads();
  for(int o = 1; o < 512; o <<= 1){
    int y = (t >= o) ? lds[t - o] : 0;
    __syncthreads();
    lds[t] += y;
    __syncthreads();
  }
  if(i < NN) rowptr[i] = lds[t] - x;
  if(t == 511) part[blockIdx.x] = lds[511];
}

__global__ void k_scanB(int* __restrict__ part, int* __restrict__ rowptr){
  if(threadIdx.x == 0 && blockIdx.x == 0){
    int run = 0;
    for(int b = 0; b < 98; b++){ int tt = part[b]; part[b] = run; run += tt; }
    rowptr[NN] = run;
  }
}

__global__ __launch_bounds__(512) void k_scanC(int* __restrict__ rowptr,
                                               const int* __restrict__ part,
                                               int* __restrict__ cursor){
  int i = blockIdx.x * 512 + threadIdx.x;
  if(i < NN){
    int val = rowptr[i] + part[blockIdx.x];
    rowptr[i] = val;
    cursor[i] = val;
  }
}

__global__ __launch_bounds__(256) void k_fill(const int* __restrict__ u, const int* __restrict__ v,
                                              int* __restrict__ cursor, int2* __restrict__ ebuf){
  int e = blockIdx.x * 256 + threadIdx.x;
  if(e < NE){
    int pos = atomicAdd(&cursor[v[e]], 1);
    ebuf[pos] = make_int2(u[e], e);
  }
}

// ---------------- layer-1 aggregation (unroll-4 for MLP) ----------------
// msg cols: [0,64) = nfb[src] (bf16), [64,128) = ef[edge] (f32 direct).
// 64 lanes/node, 2 cols/lane. Unroll-4: batch ebuf loads, then issue 4
// independent gathers -> 4x outstanding requests per wave.
__global__ __launch_bounds__(256) void k_agg1(const int* __restrict__ rowptr,
                                              const int2* __restrict__ ebuf,
                                              const unsigned short* __restrict__ nfb,
                                              const float* __restrict__ ef,
                                              unsigned short* __restrict__ hneigh1){
  int node = blockIdx.x * 4 + (threadIdx.x >> 6);
  int l = threadIdx.x & 63;
  int beg = rowptr[node], end = rowptr[node + 1];
  bool sel = l >= 32;
  int cn = 2 * l;            // nf col pair (lanes 0-31)
  int ce = 2 * (l - 32);     // ef col pair (lanes 32-63)
  float a0 = 0.f, a1 = 0.f;
  int i = beg;
  for(; i + 4 <= end; i += 4){
    int2 e0 = ebuf[i], e1 = ebuf[i + 1], e2 = ebuf[i + 2], e3 = ebuf[i + 3];
    if(sel){
      float2 t0 = *(const float2*)(ef + (size_t)((unsigned)e0.y * 64u) + ce);
      float2 t1 = *(const float2*)(ef + (size_t)((unsigned)e1.y * 64u) + ce);
      float2 t2 = *(const float2*)(ef + (size_t)((unsigned)e2.y * 64u) + ce);
      float2 t3 = *(const float2*)(ef + (size_t)((unsigned)e3.y * 64u) + ce);
      a0 += t0.x + t1.x + t2.x + t3.x;
      a1 += t0.y + t1.y + t2.y + t3.y;
    } else {
      unsigned t0 = *(const unsigned*)(nfb + (size_t)((unsigned)e0.x * 64u) + cn);
      unsigned t1 = *(const unsigned*)(nfb + (size_t)((unsigned)e1.x * 64u) + cn);
      unsigned t2 = *(const unsigned*)(nfb + (size_t)((unsigned)e2.x * 64u) + cn);
      unsigned t3 = *(const unsigned*)(nfb + (size_t)((unsigned)e3.x * 64u) + cn);
      a0 += blo(t0) + blo(t1) + blo(t2) + blo(t3);
      a1 += bhi(t0) + bhi(t1) + bhi(t2) + bhi(t3);
    }
  }
  for(; i < end; i++){
    int2 e = ebuf[i];
    if(sel){
      float2 t = *(const float2*)(ef + (size_t)((unsigned)e.y * 64u) + ce);
      a0 += t.x; a1 += t.y;
    } else {
      unsigned t = *(const unsigned*)(nfb + (size_t)((unsigned)e.x * 64u) + cn);
      a0 += blo(t); a1 += bhi(t);
    }
  }
  float inv = 1.f / fmaxf((float)(end - beg), 1.f);
  unsigned o = (unsigned)f2b(a0 * inv) | ((unsigned)f2b(a1 * inv) << 16);
  *(unsigned*)(hneigh1 + (size_t)node * 128 + 2 * l) = o;
}

// ---------------- layer-2 aggregation (unroll-4 for MLP) ----------------
// msg cols: [0,128) = hn1[src], [128,256) = relu(P1[src]+Q1[node]+b1e). 4 cols/lane.
__global__ __launch_bounds__(256) void k_agg2(const int* __restrict__ rowptr,
                                              const int2* __restrict__ ebuf,
                                              const unsigned short* __restrict__ hn1,
                                              const unsigned short* __restrict__ PQ1,
                                              const float* __restrict__ b1e,
                                              unsigned short* __restrict__ hneigh2){
  int node = blockIdx.x * 4 + (threadIdx.x >> 6);
  int l = threadIdx.x & 63;
  int beg = rowptr[node], end = rowptr[node + 1];
  bool sel = l >= 32;
  int c4 = sel ? 4 * (l - 32) : 4 * l;
  const unsigned short* base = sel ? (PQ1 + c4) : (hn1 + c4);
  unsigned stride = sel ? 256u : 128u;
  float q0 = 0.f, q1 = 0.f, q2 = 0.f, q3 = 0.f, fl = -__builtin_inff();
  if(sel){
    uint2 qq = *(const uint2*)(PQ1 + (size_t)node * 256 + 128 + c4);
    q0 = blo(qq.x) + b1e[c4];
    q1 = bhi(qq.x) + b1e[c4 + 1];
    q2 = blo(qq.y) + b1e[c4 + 2];
    q3 = bhi(qq.y) + b1e[c4 + 3];
    fl = 0.f;
  }
  const int* eb = (const int*)ebuf;   // only .x (src) needed
  float a0 = 0.f, a1 = 0.f, a2 = 0.f, a3 = 0.f;
  int i = beg;
  for(; i + 4 <= end; i += 4){
    unsigned s0 = (unsigned)eb[2 * i];
    unsigned s1 = (unsigned)eb[2 * i + 2];
    unsigned s2 = (unsigned)eb[2 * i + 4];
    unsigned s3 = (unsigned)eb[2 * i + 6];
    uint2 t0 = *(const uint2*)(base + (size_t)(s0 * stride));
    uint2 t1 = *(const uint2*)(base + (size_t)(s1 * stride));
    uint2 t2 = *(const uint2*)(base + (size_t)(s2 * stride));
    uint2 t3 = *(const uint2*)(base + (size_t)(s3 * stride));
    a0 += fmaxf(blo(t0.x) + q0, fl) + fmaxf(blo(t1.x) + q0, fl)
        + fmaxf(blo(t2.x) + q0, fl) + fmaxf(blo(t3.x) + q0, fl);
    a1 += fmaxf(bhi(t0.x) + q1, fl) + fmaxf(bhi(t1.x) + q1, fl)
        + fmaxf(bhi(t2.x) + q1, fl) + fmaxf(bhi(t3.x) + q1, fl);
    a2 += fmaxf(blo(t0.y) + q2, fl) + fmaxf(blo(t1.y) + q2, fl)
        + fmaxf(blo(t2.y) + q2, fl) + fmaxf(blo(t3.y) + q2, fl);
    a3 += fmaxf(bhi(t0.y) + q3, fl) + fmaxf(bhi(t1.y) + q3, fl)
        + fmaxf(bhi(t2.y) + q3, fl) + fmaxf(bhi(t3.y) + q3, fl);
  }
  for(; i < end; i++){
    unsigned s = (unsigned)eb[2 * i];
    uint2 t = *(const uint2*)(base + (size_t)(s * stride));
    a0 += fmaxf(blo(t.x) + q0, fl);
    a1 += fmaxf(bhi(t.x) + q1, fl);
    a2 += fmaxf(blo(t.y) + q2, fl);
    a3 += fmaxf(bhi(t.y) + q3, fl);
  }
  float inv = 1.f / fmaxf((float)(end - beg), 1.f);
  unsigned o0 = (unsigned)f2b(a0 * inv) | ((unsigned)f2b(a1 * inv) << 16);
  unsigned o1 = (unsigned)f2b(a2 * inv) | ((unsigned)f2b(a3 * inv) << 16);
  *(uint2*)(hneigh2 + (size_t)node * 256 + 4 * l) = make_uint2(o0, o1);
}

// ---------------- final edge output ----------------
__global__ __launch_bounds__(256) void k_he2(const int* __restrict__ u, const int* __restrict__ v,
                                             const unsigned short* __restrict__ PQ2,
                                             const float* __restrict__ b2e,
                                             float* __restrict__ outp){
  int idx = blockIdx.x * 256 + threadIdx.x;
  int e = idx >> 5;
  if(e >= NE) return;
  int c = (idx & 31) * 4;
  int uu = u[e], vv = v[e];
  uint2 p = *(const uint2*)(PQ2 + (size_t)uu * 256 + c);
  uint2 q = *(const uint2*)(PQ2 + (size_t)vv * 256 + 128 + c);
  float4 b = *(const float4*)(b2e + c);
  float4 r;
  r.x = fmaxf(blo(p.x) + blo(q.x) + b.x, 0.f);
  r.y = fmaxf(bhi(p.x) + bhi(q.x) + b.y, 0.f);
  r.z = fmaxf(blo(p.y) + blo(q.y) + b.z, 0.f);
  r.w = fmaxf(bhi(p.y) + bhi(q.y) + b.w, 0.f);
  *(float4*)(outp + (size_t)e * 128 + c) = r;
}

// ---------------- GEMM: C = [A0|A1] @ B (+bias, relu), bf16 MFMA, LDS-free ----------------
// B packed layout (stride 32), B panels are small (<=96KB) and L2-resident: load
// fragments straight from global. No barriers, no LDS -> max occupancy.
// Block: 4 waves, 128 rows; grid.y = N/128 col blocks. Wave: 32 rows x 128 cols.
// OM: 0 = f32 out, 1 = bf16 out, 2 = both.
template<int K, int N, bool BR, int OM>
__global__ __launch_bounds__(256) void k_gemm(const unsigned short* __restrict__ A0, int W0,
                                              const unsigned short* __restrict__ A1, int W1,
                                              const unsigned short* __restrict__ Bs,
                                              const float* __restrict__ bias,
                                              float* __restrict__ Cf,
                                              unsigned short* __restrict__ Cb){
  constexpr int KT = K / 32;
  const int nb = blockIdx.y;
  const int wid = threadIdx.x >> 6, lane = threadIdx.x & 63;
  const int ln = lane & 15, kg = lane >> 4;
  const int r0 = blockIdx.x * 128 + wid * 32;
  int r_[2];
  r_[0] = min(r0 + ln, NN - 1);
  r_[1] = min(r0 + 16 + ln, NN - 1);

  floatx4 acc[2][8];
#pragma unroll
  for(int a = 0; a < 2; a++)
#pragma unroll
    for(int b = 0; b < 8; b++) acc[a][b] = (floatx4){0.f, 0.f, 0.f, 0.f};

#pragma unroll
  for(int kt = 0; kt < KT; kt++){
    int k = kt * 32 + kg * 8;
    short8 af[2];
#pragma unroll
    for(int mt = 0; mt < 2; mt++){
      const unsigned short* p = (k < W0) ? (A0 + (size_t)r_[mt] * W0 + k)
                                         : (A1 + (size_t)r_[mt] * W1 + (k - W0));
      af[mt] = *(const short8*)p;
    }
    const unsigned short* bp = Bs + ((size_t)(kt * N + nb * 128)) * 32 + kg * 8;
#pragma unroll
    for(int nt = 0; nt < 8; nt++){
      short8 bfrag = *(const short8*)(bp + (nt * 16 + ln) * 32);
      acc[0][nt] = __builtin_amdgcn_mfma_f32_16x16x32_bf16(af[0], bfrag, acc[0][nt], 0, 0, 0);
      acc[1][nt] = __builtin_amdgcn_mfma_f32_16x16x32_bf16(af[1], bfrag, acc[1][nt], 0, 0, 0);
    }
  }
  // epilogue: C/D layout col = lane&15, row = (lane>>4)*4 + reg  [m89/m91 verified]
#pragma unroll
  for(int mt = 0; mt < 2; mt++){
    int rb = r0 + mt * 16 + kg * 4;
#pragma unroll
    for(int nt = 0; nt < 8; nt++){
      int col = nb * 128 + nt * 16 + ln;
      float bv = BR ? bias[col] : 0.f;
#pragma unroll
      for(int rr = 0; rr < 4; rr++){
        int row = rb + rr;
        if(row < NN){
          float vv = acc[mt][nt][rr];
          if(BR) vv = fmaxf(vv + bv, 0.f);
          if(OM == 0 || OM == 2) Cf[(size_t)row * N + col] = vv;
          if(OM == 1 || OM == 2) Cb[(size_t)row * N + col] = f2b(vv);
        }
      }
    }
  }
}

extern "C" void kernel_launch(void* const* d_in, const int* in_sizes, int n_in,
                              void* d_out, int out_size, void* d_ws, size_t ws_size,
                              hipStream_t stream){
  const float* nf  = (const float*)d_in[0];
  const float* ef  = (const float*)d_in[1];
  const float* W1a = (const float*)d_in[2];
  const float* b1a = (const float*)d_in[3];
  const float* W1e = (const float*)d_in[4];
  const float* b1e = (const float*)d_in[5];
  const float* W2a = (const float*)d_in[6];
  const float* b2a = (const float*)d_in[7];
  const float* W2e = (const float*)d_in[8];
  const float* b2e = (const float*)d_in[9];
  const int*   u   = (const int*)d_in[10];
  const int*   v   = (const int*)d_in[11];

  char* ws = (char*)d_ws;
  int* rowptr = (int*)(ws + 0);               // 50001 ints
  int* cnt    = (int*)(ws + 0x40000);         // 50000 ints (hist, then cursor)
  int* part   = (int*)(ws + 0x80000);         // 98 ints
  unsigned short* w1as = (unsigned short*)(ws + 0x90000);   // 48 KB
  unsigned short* w1es = (unsigned short*)(ws + 0xA0000);   // 64 KB
  unsigned short* w2as = (unsigned short*)(ws + 0xC0000);   // 96 KB
  unsigned short* w2es = (unsigned short*)(ws + 0xE0000);   // 64 KB
  unsigned short* nfb  = (unsigned short*)(ws + (size_t)(1u   << 20));  // 6.4 MB
  int2*           ebuf = (int2*)          (ws + (size_t)(8u   << 20));  // 6.4 MB
  unsigned short* hn1b = (unsigned short*)(ws + (size_t)(15u  << 20));  // 12.8 MB
  unsigned short* hn2b = (unsigned short*)(ws + (size_t)(28u  << 20));  // 12.8 MB
  unsigned short* PQ   = (unsigned short*)(ws + (size_t)(41u  << 20));  // 25.6 MB
  unsigned short* hnb1 = (unsigned short*)(ws + (size_t)(67u  << 20));  // 12.8 MB
  unsigned short* hnb2 = (unsigned short*)(ws + (size_t)(80u  << 20));  // 25.6 MB

  hipMemsetAsync(ws + 0x40000, 0, 0x40200, stream);   // zero cnt + part

  // fused prep: nf -> bf16, histogram, weight swizzles (ef stays f32)
  k_prep<<<NB_NF + NB_HIST + NB_W1A + NB_W1E + NB_W2A + NB_W2E, 256, 0, stream>>>(
      nf, W1a, W1e, W2a, W2e, v, nfb, w1as, w1es, w2as, w2es, cnt);

  // CSR
  k_scanA<<<98, 512, 0, stream>>>(cnt, rowptr, part);
  k_scanB<<<1,  64,  0, stream>>>(part, rowptr);
  k_scanC<<<98, 512, 0, stream>>>(rowptr, part, cnt);
  k_fill <<<3125, 256, 0, stream>>>(u, v, cnt, ebuf);

  // layer 1
  k_agg1<<<12500, 256, 0, stream>>>(rowptr, ebuf, nfb, ef, hnb1);
  k_gemm<192, 128, true,  1><<<dim3(391, 1), 256, 0, stream>>>(nfb, 64, hnb1, 128, w1as, b1a, nullptr, hn1b);
  k_gemm<128, 256, false, 1><<<dim3(391, 2), 256, 0, stream>>>(hn1b, 128, hn1b, 128, w1es, nullptr, nullptr, PQ);

  // layer 2
  k_agg2<<<12500, 256, 0, stream>>>(rowptr, ebuf, hn1b, PQ, b1e, hnb2);
  k_gemm<384, 128, true,  2><<<dim3(391, 1), 256, 0, stream>>>(hn1b, 128, hnb2, 256, w2as, b2a, (float*)d_out, hn2b);
  k_gemm<128, 256, false, 1><<<dim3(391, 2), 256, 0, stream>>>(hn2b, 128, hn2b, 128, w2es, nullptr, nullptr, PQ);
  k_he2<<<100000, 256, 0, stream>>>(u, v, PQ, b2e, (float*)d_out + (size_t)NN * 128);
}

// Round 4
// 920.277 us; speedup vs baseline: 1.1038x; 1.0246x over previous
//
#include <hip/hip_runtime.h>

#define NN 50000
#define NE 800000

typedef __attribute__((ext_vector_type(8))) short short8;
typedef __attribute__((ext_vector_type(4))) float floatx4;

__device__ __forceinline__ unsigned short f2b(float f){
  unsigned u = __float_as_uint(f);
  u += 0x7fffu + ((u >> 16) & 1u);
  return (unsigned short)(u >> 16);
}
__device__ __forceinline__ float blo(unsigned u){ return __uint_as_float(u << 16); }
__device__ __forceinline__ float bhi(unsigned u){ return __uint_as_float(u & 0xffff0000u); }

// ---------------- fused prep: nf->bf16, hist, weight swizzles ----------------
// packed B layout (stride 32): dst[((k>>5)*N + n)*32 + (k&31)]
#define NB_NF   3125           // NN*64/4 float4 / 256
#define NB_HIST 3125           // NE/256
#define NB_W1A  96             // 192*128/256
#define NB_W1E  128            // 128*256/256
#define NB_W2A  192            // 384*128/256
#define NB_W2E  128

__global__ __launch_bounds__(256) void k_prep(const float* __restrict__ nf,
                                              const float* __restrict__ W1a,
                                              const float* __restrict__ W1e,
                                              const float* __restrict__ W2a,
                                              const float* __restrict__ W2e,
                                              const int* __restrict__ v,
                                              unsigned short* __restrict__ nfb,
                                              unsigned short* __restrict__ w1as,
                                              unsigned short* __restrict__ w1es,
                                              unsigned short* __restrict__ w2as,
                                              unsigned short* __restrict__ w2es,
                                              int* __restrict__ cnt){
  int b = blockIdx.x, t = threadIdx.x;
  if(b < NB_NF){
    int i = b * 256 + t;
    float4 vv = ((const float4*)nf)[i];
    unsigned a = (unsigned)f2b(vv.x) | ((unsigned)f2b(vv.y) << 16);
    unsigned c = (unsigned)f2b(vv.z) | ((unsigned)f2b(vv.w) << 16);
    ((uint2*)nfb)[i] = make_uint2(a, c);
  } else if(b < NB_NF + NB_HIST){
    int e = (b - NB_NF) * 256 + t;
    if(e < NE) atomicAdd(&cnt[v[e]], 1);
  } else if(b < NB_NF + NB_HIST + NB_W1A){
    int i = (b - NB_NF - NB_HIST) * 256 + t;        // 192x128
    int k = i >> 7, n = i & 127;
    w1as[((k >> 5) * 128 + n) * 32 + (k & 31)] = f2b(W1a[i]);
  } else if(b < NB_NF + NB_HIST + NB_W1A + NB_W1E){
    int i = (b - NB_NF - NB_HIST - NB_W1A) * 256 + t; // 128x256 view of 256x128
    int k = i >> 8, n = i & 255;
    float val = W1e[(size_t)(k + ((n >> 7) << 7)) * 128 + (n & 127)];
    w1es[((k >> 5) * 256 + n) * 32 + (k & 31)] = f2b(val);
  } else if(b < NB_NF + NB_HIST + NB_W1A + NB_W1E + NB_W2A){
    int i = (b - NB_NF - NB_HIST - NB_W1A - NB_W1E) * 256 + t; // 384x128
    int k = i >> 7, n = i & 127;
    w2as[((k >> 5) * 128 + n) * 32 + (k & 31)] = f2b(W2a[i]);
  } else {
    int i = (b - NB_NF - NB_HIST - NB_W1A - NB_W1E - NB_W2A) * 256 + t;
    int k = i >> 8, n = i & 255;
    float val = W2e[(size_t)(k + ((n >> 7) << 7)) * 128 + (n & 127)];
    w2es[((k >> 5) * 256 + n) * 32 + (k & 31)] = f2b(val);
  }
}

// ---------------- CSR scan + fill ----------------
__global__ __launch_bounds__(512) void k_scanA(const int* __restrict__ cnt,
                                               int* __restrict__ rowptr,
                                               int* __restrict__ part){
  __shared__ int lds[512];
  int t = threadIdx.x;
  int i = blockIdx.x * 512 + t;
  int x = (i < NN) ? cnt[i] : 0;
  lds[t] = x;
  __syncthreads();
  for(int o = 1; o < 512; o <<= 1){
    int y = (t >= o) ? lds[t - o] : 0;
    __syncthreads();
    lds[t] += y;
    __syncthreads();
  }
  if(i < NN) rowptr[i] = lds[t] - x;
  if(t == 511) part[blockIdx.x] = lds[511];
}

__global__ void k_scanB(int* __restrict__ part, int* __restrict__ rowptr){
  if(threadIdx.x == 0 && blockIdx.x == 0){
    int run = 0;
    for(int b = 0; b < 98; b++){ int tt = part[b]; part[b] = run; run += tt; }
    rowptr[NN] = run;
  }
}

__global__ __launch_bounds__(512) void k_scanC(int* __restrict__ rowptr,
                                               const int* __restrict__ part,
                                               int* __restrict__ cursor){
  int i = blockIdx.x * 512 + threadIdx.x;
  if(i < NN){
    int val = rowptr[i] + part[blockIdx.x];
    rowptr[i] = val;
    cursor[i] = val;
  }
}

__global__ __launch_bounds__(256) void k_fill(const int* __restrict__ u, const int* __restrict__ v,
                                              int* __restrict__ cursor, int2* __restrict__ ebuf){
  int e = blockIdx.x * 256 + threadIdx.x;
  if(e < NE){
    int pos = atomicAdd(&cursor[v[e]], 1);
    ebuf[pos] = make_int2(u[e], e);
  }
}

// ---------------- layer-1 aggregation: 2 edges/iter, unroll-4 (8 in flight) ----
// Wave: halves h=0/1 work on edges i+h. Within a half (32 lanes):
//   lanes g=0..15  : nfb[src] cols 4g..4g+3 (bf16, uint2 = 8B)
//   lanes g=16..31 : ef[edge] cols 4(g-16)..+3 (f32, float4 = 16B)
// Final: halves combined with shfl_xor(32); lanes 0..31 store.
__global__ __launch_bounds__(256) void k_agg1(const int* __restrict__ rowptr,
                                              const int2* __restrict__ ebuf,
                                              const unsigned short* __restrict__ nfb,
                                              const float* __restrict__ ef,
                                              unsigned short* __restrict__ hneigh1){
  int node = blockIdx.x * 4 + (threadIdx.x >> 6);
  int l = threadIdx.x & 63;
  int h = l >> 5;
  int g = l & 31;
  bool sel = g >= 16;
  int beg = rowptr[node], end = rowptr[node + 1];
  const unsigned short* nbase = nfb + 4 * g;
  const float* ebase = ef + 4 * (g - 16);
  float a0 = 0.f, a1 = 0.f, a2 = 0.f, a3 = 0.f;
  int i = beg;
  for(; i + 8 <= end; i += 8){
    int2 e0 = ebuf[i + h], e1 = ebuf[i + 2 + h], e2 = ebuf[i + 4 + h], e3 = ebuf[i + 6 + h];
    if(sel){
      float4 t0 = *(const float4*)(ebase + (size_t)((unsigned)e0.y) * 64u);
      float4 t1 = *(const float4*)(ebase + (size_t)((unsigned)e1.y) * 64u);
      float4 t2 = *(const float4*)(ebase + (size_t)((unsigned)e2.y) * 64u);
      float4 t3 = *(const float4*)(ebase + (size_t)((unsigned)e3.y) * 64u);
      a0 += t0.x + t1.x + t2.x + t3.x;
      a1 += t0.y + t1.y + t2.y + t3.y;
      a2 += t0.z + t1.z + t2.z + t3.z;
      a3 += t0.w + t1.w + t2.w + t3.w;
    } else {
      uint2 t0 = *(const uint2*)(nbase + (size_t)((unsigned)e0.x) * 64u);
      uint2 t1 = *(const uint2*)(nbase + (size_t)((unsigned)e1.x) * 64u);
      uint2 t2 = *(const uint2*)(nbase + (size_t)((unsigned)e2.x) * 64u);
      uint2 t3 = *(const uint2*)(nbase + (size_t)((unsigned)e3.x) * 64u);
      a0 += blo(t0.x) + blo(t1.x) + blo(t2.x) + blo(t3.x);
      a1 += bhi(t0.x) + bhi(t1.x) + bhi(t2.x) + bhi(t3.x);
      a2 += blo(t0.y) + blo(t1.y) + blo(t2.y) + blo(t3.y);
      a3 += bhi(t0.y) + bhi(t1.y) + bhi(t2.y) + bhi(t3.y);
    }
  }
  for(; i + 2 <= end; i += 2){
    int2 e = ebuf[i + h];
    if(sel){
      float4 t = *(const float4*)(ebase + (size_t)((unsigned)e.y) * 64u);
      a0 += t.x; a1 += t.y; a2 += t.z; a3 += t.w;
    } else {
      uint2 t = *(const uint2*)(nbase + (size_t)((unsigned)e.x) * 64u);
      a0 += blo(t.x); a1 += bhi(t.x); a2 += blo(t.y); a3 += bhi(t.y);
    }
  }
  if(h == 0 && i < end){
    int2 e = ebuf[i];
    if(sel){
      float4 t = *(const float4*)(ebase + (size_t)((unsigned)e.y) * 64u);
      a0 += t.x; a1 += t.y; a2 += t.z; a3 += t.w;
    } else {
      uint2 t = *(const uint2*)(nbase + (size_t)((unsigned)e.x) * 64u);
      a0 += blo(t.x); a1 += bhi(t.x); a2 += blo(t.y); a3 += bhi(t.y);
    }
  }
  a0 += __shfl_xor(a0, 32);
  a1 += __shfl_xor(a1, 32);
  a2 += __shfl_xor(a2, 32);
  a3 += __shfl_xor(a3, 32);
  if(h == 0){
    float inv = 1.f / fmaxf((float)(end - beg), 1.f);
    unsigned o0 = (unsigned)f2b(a0 * inv) | ((unsigned)f2b(a1 * inv) << 16);
    unsigned o1 = (unsigned)f2b(a2 * inv) | ((unsigned)f2b(a3 * inv) << 16);
    int c = sel ? (64 + 4 * (g - 16)) : (4 * g);
    *(uint2*)(hneigh1 + (size_t)node * 128 + c) = make_uint2(o0, o1);
  }
}

// ---------------- layer-2 aggregation: 2 edges/iter, unroll-4 ----------------
// Within a half (32 lanes): lanes 0..15: hn1[src] cols 8g.. (uint4 16B);
// lanes 16..31: P1[src] cols 8(g-16).. with relu(P+Q+b) (uint4 16B).
__global__ __launch_bounds__(256) void k_agg2(const int* __restrict__ rowptr,
                                              const int2* __restrict__ ebuf,
                                              const unsigned short* __restrict__ hn1,
                                              const unsigned short* __restrict__ PQ1,
                                              const float* __restrict__ b1e,
                                              unsigned short* __restrict__ hneigh2){
  int node = blockIdx.x * 4 + (threadIdx.x >> 6);
  int l = threadIdx.x & 63;
  int h = l >> 5;
  int g = l & 31;
  bool sel = g >= 16;
  int beg = rowptr[node], end = rowptr[node + 1];
  int c8 = sel ? 8 * (g - 16) : 8 * g;
  const unsigned short* base = sel ? (PQ1 + c8) : (hn1 + c8);
  unsigned stride = sel ? 256u : 128u;
  float q[8];
  float fl = -__builtin_inff();
#pragma unroll
  for(int j = 0; j < 8; j++) q[j] = 0.f;
  if(sel){
    uint4 qq = *(const uint4*)(PQ1 + (size_t)node * 256 + 128 + c8);
    float4 b0 = *(const float4*)(b1e + c8);
    float4 b1 = *(const float4*)(b1e + c8 + 4);
    q[0] = blo(qq.x) + b0.x; q[1] = bhi(qq.x) + b0.y;
    q[2] = blo(qq.y) + b0.z; q[3] = bhi(qq.y) + b0.w;
    q[4] = blo(qq.z) + b1.x; q[5] = bhi(qq.z) + b1.y;
    q[6] = blo(qq.w) + b1.z; q[7] = bhi(qq.w) + b1.w;
    fl = 0.f;
  }
  const int* eb = (const int*)ebuf;   // only .x (src) needed
  float a[8];
#pragma unroll
  for(int j = 0; j < 8; j++) a[j] = 0.f;
  int i = beg;
  for(; i + 8 <= end; i += 8){
    unsigned s0 = (unsigned)eb[2 * (i + h)];
    unsigned s1 = (unsigned)eb[2 * (i + 2 + h)];
    unsigned s2 = (unsigned)eb[2 * (i + 4 + h)];
    unsigned s3 = (unsigned)eb[2 * (i + 6 + h)];
    uint4 t0 = *(const uint4*)(base + (size_t)(s0 * stride));
    uint4 t1 = *(const uint4*)(base + (size_t)(s1 * stride));
    uint4 t2 = *(const uint4*)(base + (size_t)(s2 * stride));
    uint4 t3 = *(const uint4*)(base + (size_t)(s3 * stride));
    a[0] += fmaxf(blo(t0.x) + q[0], fl) + fmaxf(blo(t1.x) + q[0], fl)
          + fmaxf(blo(t2.x) + q[0], fl) + fmaxf(blo(t3.x) + q[0], fl);
    a[1] += fmaxf(bhi(t0.x) + q[1], fl) + fmaxf(bhi(t1.x) + q[1], fl)
          + fmaxf(bhi(t2.x) + q[1], fl) + fmaxf(bhi(t3.x) + q[1], fl);
    a[2] += fmaxf(blo(t0.y) + q[2], fl) + fmaxf(blo(t1.y) + q[2], fl)
          + fmaxf(blo(t2.y) + q[2], fl) + fmaxf(blo(t3.y) + q[2], fl);
    a[3] += fmaxf(bhi(t0.y) + q[3], fl) + fmaxf(bhi(t1.y) + q[3], fl)
          + fmaxf(bhi(t2.y) + q[3], fl) + fmaxf(bhi(t3.y) + q[3], fl);
    a[4] += fmaxf(blo(t0.z) + q[4], fl) + fmaxf(blo(t1.z) + q[4], fl)
          + fmaxf(blo(t2.z) + q[4], fl) + fmaxf(blo(t3.z) + q[4], fl);
    a[5] += fmaxf(bhi(t0.z) + q[5], fl) + fmaxf(bhi(t1.z) + q[5], fl)
          + fmaxf(bhi(t2.z) + q[5], fl) + fmaxf(bhi(t3.z) + q[5], fl);
    a[6] += fmaxf(blo(t0.w) + q[6], fl) + fmaxf(blo(t1.w) + q[6], fl)
          + fmaxf(blo(t2.w) + q[6], fl) + fmaxf(blo(t3.w) + q[6], fl);
    a[7] += fmaxf(bhi(t0.w) + q[7], fl) + fmaxf(bhi(t1.w) + q[7], fl)
          + fmaxf(bhi(t2.w) + q[7], fl) + fmaxf(bhi(t3.w) + q[7], fl);
  }
  for(; i + 2 <= end; i += 2){
    unsigned s = (unsigned)eb[2 * (i + h)];
    uint4 t = *(const uint4*)(base + (size_t)(s * stride));
    a[0] += fmaxf(blo(t.x) + q[0], fl);
    a[1] += fmaxf(bhi(t.x) + q[1], fl);
    a[2] += fmaxf(blo(t.y) + q[2], fl);
    a[3] += fmaxf(bhi(t.y) + q[3], fl);
    a[4] += fmaxf(blo(t.z) + q[4], fl);
    a[5] += fmaxf(bhi(t.z) + q[5], fl);
    a[6] += fmaxf(blo(t.w) + q[6], fl);
    a[7] += fmaxf(bhi(t.w) + q[7], fl);
  }
  if(h == 0 && i < end){
    unsigned s = (unsigned)eb[2 * i];
    uint4 t = *(const uint4*)(base + (size_t)(s * stride));
    a[0] += fmaxf(blo(t.x) + q[0], fl);
    a[1] += fmaxf(bhi(t.x) + q[1], fl);
    a[2] += fmaxf(blo(t.y) + q[2], fl);
    a[3] += fmaxf(bhi(t.y) + q[3], fl);
    a[4] += fmaxf(blo(t.z) + q[4], fl);
    a[5] += fmaxf(bhi(t.z) + q[5], fl);
    a[6] += fmaxf(blo(t.w) + q[6], fl);
    a[7] += fmaxf(bhi(t.w) + q[7], fl);
  }
#pragma unroll
  for(int j = 0; j < 8; j++) a[j] += __shfl_xor(a[j], 32);
  if(h == 0){
    float inv = 1.f / fmaxf((float)(end - beg), 1.f);
    unsigned o0 = (unsigned)f2b(a[0] * inv) | ((unsigned)f2b(a[1] * inv) << 16);
    unsigned o1 = (unsigned)f2b(a[2] * inv) | ((unsigned)f2b(a[3] * inv) << 16);
    unsigned o2 = (unsigned)f2b(a[4] * inv) | ((unsigned)f2b(a[5] * inv) << 16);
    unsigned o3 = (unsigned)f2b(a[6] * inv) | ((unsigned)f2b(a[7] * inv) << 16);
    int c = sel ? (128 + 8 * (g - 16)) : (8 * g);
    *(uint4*)(hneigh2 + (size_t)node * 256 + c) = make_uint4(o0, o1, o2, o3);
  }
}

// ---------------- final edge output: 16 lanes/edge, 8 cols/lane --------------
__global__ __launch_bounds__(256) void k_he2(const int* __restrict__ u, const int* __restrict__ v,
                                             const unsigned short* __restrict__ PQ2,
                                             const float* __restrict__ b2e,
                                             float* __restrict__ outp){
  int idx = blockIdx.x * 256 + threadIdx.x;
  int e = idx >> 4;
  if(e >= NE) return;
  int c = (idx & 15) * 8;
  int uu = u[e], vv = v[e];
  uint4 p = *(const uint4*)(PQ2 + (size_t)uu * 256 + c);
  uint4 q = *(const uint4*)(PQ2 + (size_t)vv * 256 + 128 + c);
  float4 b0 = *(const float4*)(b2e + c);
  float4 b1 = *(const float4*)(b2e + c + 4);
  float4 r0, r1;
  r0.x = fmaxf(blo(p.x) + blo(q.x) + b0.x, 0.f);
  r0.y = fmaxf(bhi(p.x) + bhi(q.x) + b0.y, 0.f);
  r0.z = fmaxf(blo(p.y) + blo(q.y) + b0.z, 0.f);
  r0.w = fmaxf(bhi(p.y) + bhi(q.y) + b0.w, 0.f);
  r1.x = fmaxf(blo(p.z) + blo(q.z) + b1.x, 0.f);
  r1.y = fmaxf(bhi(p.z) + bhi(q.z) + b1.y, 0.f);
  r1.z = fmaxf(blo(p.w) + blo(q.w) + b1.z, 0.f);
  r1.w = fmaxf(bhi(p.w) + bhi(q.w) + b1.w, 0.f);
  *(float4*)(outp + (size_t)e * 128 + c) = r0;
  *(float4*)(outp + (size_t)e * 128 + c + 4) = r1;
}

// ---------------- GEMM: C = [A0|A1] @ B (+bias, relu), bf16 MFMA, LDS-free ----------------
// 16 rows/wave, 64 rows/block (grid.x = 782) -> 2x waves vs 128-row blocks for
// latency hiding of the global B-fragment loads. B panels L2-resident.
// OM: 0 = f32 out, 1 = bf16 out, 2 = both.
template<int K, int N, bool BR, int OM>
__global__ __launch_bounds__(256) void k_gemm(const unsigned short* __restrict__ A0, int W0,
                                              const unsigned short* __restrict__ A1, int W1,
                                              const unsigned short* __restrict__ Bs,
                                              const float* __restrict__ bias,
                                              float* __restrict__ Cf,
                                              unsigned short* __restrict__ Cb){
  constexpr int KT = K / 32;
  const int nb = blockIdx.y;
  const int wid = threadIdx.x >> 6, lane = threadIdx.x & 63;
  const int ln = lane & 15, kg = lane >> 4;
  const int r0 = blockIdx.x * 64 + wid * 16;
  int r = min(r0 + ln, NN - 1);

  floatx4 acc[8];
#pragma unroll
  for(int b = 0; b < 8; b++) acc[b] = (floatx4){0.f, 0.f, 0.f, 0.f};

#pragma unroll
  for(int kt = 0; kt < KT; kt++){
    int k = kt * 32 + kg * 8;
    const unsigned short* p = (k < W0) ? (A0 + (size_t)r * W0 + k)
                                       : (A1 + (size_t)r * W1 + (k - W0));
    short8 af = *(const short8*)p;
    const unsigned short* bp = Bs + ((size_t)(kt * N + nb * 128)) * 32 + kg * 8;
#pragma unroll
    for(int nt = 0; nt < 8; nt++){
      short8 bfrag = *(const short8*)(bp + (nt * 16 + ln) * 32);
      acc[nt] = __builtin_amdgcn_mfma_f32_16x16x32_bf16(af, bfrag, acc[nt], 0, 0, 0);
    }
  }
  // epilogue: C/D layout col = lane&15, row = (lane>>4)*4 + reg  [m89/m91 verified]
  int rb = r0 + kg * 4;
#pragma unroll
  for(int nt = 0; nt < 8; nt++){
    int col = nb * 128 + nt * 16 + ln;
    float bv = BR ? bias[col] : 0.f;
#pragma unroll
    for(int rr = 0; rr < 4; rr++){
      int row = rb + rr;
      if(row < NN){
        float vv = acc[nt][rr];
        if(BR) vv = fmaxf(vv + bv, 0.f);
        if(OM == 0 || OM == 2) Cf[(size_t)row * N + col] = vv;
        if(OM == 1 || OM == 2) Cb[(size_t)row * N + col] = f2b(vv);
      }
    }
  }
}

extern "C" void kernel_launch(void* const* d_in, const int* in_sizes, int n_in,
                              void* d_out, int out_size, void* d_ws, size_t ws_size,
                              hipStream_t stream){
  const float* nf  = (const float*)d_in[0];
  const float* ef  = (const float*)d_in[1];
  const float* W1a = (const float*)d_in[2];
  const float* b1a = (const float*)d_in[3];
  const float* W1e = (const float*)d_in[4];
  const float* b1e = (const float*)d_in[5];
  const float* W2a = (const float*)d_in[6];
  const float* b2a = (const float*)d_in[7];
  const float* W2e = (const float*)d_in[8];
  const float* b2e = (const float*)d_in[9];
  const int*   u   = (const int*)d_in[10];
  const int*   v   = (const int*)d_in[11];

  char* ws = (char*)d_ws;
  int* rowptr = (int*)(ws + 0);               // 50001 ints
  int* cnt    = (int*)(ws + 0x40000);         // 50000 ints (hist, then cursor)
  int* part   = (int*)(ws + 0x80000);         // 98 ints
  unsigned short* w1as = (unsigned short*)(ws + 0x90000);   // 48 KB
  unsigned short* w1es = (unsigned short*)(ws + 0xA0000);   // 64 KB
  unsigned short* w2as = (unsigned short*)(ws + 0xC0000);   // 96 KB
  unsigned short* w2es = (unsigned short*)(ws + 0xE0000);   // 64 KB
  unsigned short* nfb  = (unsigned short*)(ws + (size_t)(1u   << 20));  // 6.4 MB
  int2*           ebuf = (int2*)          (ws + (size_t)(8u   << 20));  // 6.4 MB
  unsigned short* hn1b = (unsigned short*)(ws + (size_t)(15u  << 20));  // 12.8 MB
  unsigned short* hn2b = (unsigned short*)(ws + (size_t)(28u  << 20));  // 12.8 MB
  unsigned short* PQ   = (unsigned short*)(ws + (size_t)(41u  << 20));  // 25.6 MB
  unsigned short* hnb1 = (unsigned short*)(ws + (size_t)(67u  << 20));  // 12.8 MB
  unsigned short* hnb2 = (unsigned short*)(ws + (size_t)(80u  << 20));  // 25.6 MB

  hipMemsetAsync(ws + 0x40000, 0, 0x40200, stream);   // zero cnt + part

  // fused prep: nf -> bf16, histogram, weight swizzles (ef stays f32)
  k_prep<<<NB_NF + NB_HIST + NB_W1A + NB_W1E + NB_W2A + NB_W2E, 256, 0, stream>>>(
      nf, W1a, W1e, W2a, W2e, v, nfb, w1as, w1es, w2as, w2es, cnt);

  // CSR
  k_scanA<<<98, 512, 0, stream>>>(cnt, rowptr, part);
  k_scanB<<<1,  64,  0, stream>>>(part, rowptr);
  k_scanC<<<98, 512, 0, stream>>>(rowptr, part, cnt);
  k_fill <<<3125, 256, 0, stream>>>(u, v, cnt, ebuf);

  // layer 1
  k_agg1<<<12500, 256, 0, stream>>>(rowptr, ebuf, nfb, ef, hnb1);
  k_gemm<192, 128, true,  1><<<dim3(782, 1), 256, 0, stream>>>(nfb, 64, hnb1, 128, w1as, b1a, nullptr, hn1b);
  k_gemm<128, 256, false, 1><<<dim3(782, 2), 256, 0, stream>>>(hn1b, 128, hn1b, 128, w1es, nullptr, nullptr, PQ);

  // layer 2
  k_agg2<<<12500, 256, 0, stream>>>(rowptr, ebuf, hn1b, PQ, b1e, hnb2);
  k_gemm<384, 128, true,  2><<<dim3(782, 1), 256, 0, stream>>>(hn1b, 128, hnb2, 256, w2as, b2a, (float*)d_out, hn2b);
  k_gemm<128, 256, false, 1><<<dim3(782, 2), 256, 0, stream>>>(hn2b, 128, hn2b, 128, w2es, nullptr, nullptr, PQ);
  k_he2<<<50000, 256, 0, stream>>>(u, v, PQ, b2e, (float*)d_out + (size_t)NN * 128);
}